// Round 1
// baseline (1012.579 us; speedup 1.0000x reference)
//
#include <hip/hip_runtime.h>

#define BATCH   32
#define SEQ     2048
#define IN_DIM  32
#define HID     512
#define STATE   64
#define NLAYERS 4
#define NTOK    (BATCH*SEQ)          // 65536
#define EPS     1e-5f
#define KTAN    2.8853900817779268f  // 2*log2(e)

#define F4(p)  (*reinterpret_cast<float4*>(p))
#define CF4(p) (*reinterpret_cast<const float4*>(p))

__device__ __forceinline__ float fast_exp2(float x){ return __builtin_amdgcn_exp2f(x); }
__device__ __forceinline__ float fast_rcp(float x){ return __builtin_amdgcn_rcpf(x); }

// ---------------------------------------------------------------------------
// h = x @ Win + bin, plus per-row (mu, rstd) stats for the first layer's LN.
// grid = NTOK blocks x 256 threads, each thread computes 2 of 512 outputs.
__global__ __launch_bounds__(256) void k_input(const float* __restrict__ x,
    const float* __restrict__ Win, const float* __restrict__ bin,
    float* __restrict__ h, float2* __restrict__ stats)
{
  int m = blockIdx.x, tid = threadIdx.x;
  __shared__ float xs[IN_DIM];
  __shared__ float red[8];
  if (tid < IN_DIM) xs[tid] = x[m*IN_DIM + tid];
  __syncthreads();
  float a0 = bin[tid], a1 = bin[tid+256];
  #pragma unroll
  for (int k=0;k<IN_DIM;k++){
    float xv = xs[k];
    a0 = fmaf(xv, Win[k*HID + tid],       a0);
    a1 = fmaf(xv, Win[k*HID + tid + 256], a1);
  }
  h[m*HID + tid]       = a0;
  h[m*HID + tid + 256] = a1;
  float s_ = a0+a1, q = a0*a0+a1*a1;
  #pragma unroll
  for (int off=32; off; off>>=1){ s_ += __shfl_down(s_, off); q += __shfl_down(q, off); }
  int wid = tid>>6;
  if ((tid&63)==0){ red[wid]=s_; red[4+wid]=q; }
  __syncthreads();
  if (tid==0){
    s_ = red[0]+red[1]+red[2]+red[3];
    q  = red[4]+red[5]+red[6]+red[7];
    float mu  = s_*(1.f/HID);
    float var = q*(1.f/HID) - mu*mu;
    stats[m] = make_float2(mu, rsqrtf(fmaxf(var,0.f)+EPS));
  }
}

// ---------------------------------------------------------------------------
// Per layer precompute: A'[j][s] = g[j]*A[j][s], GA[s]=sum_j A', BA[s]=sum_j b[j]*A.
// grid = NLAYERS x 64 threads.
__global__ void k_prep(const float* __restrict__ A, const float* __restrict__ g,
                       const float* __restrict__ b, float* __restrict__ Ap,
                       float* __restrict__ GA, float* __restrict__ BA)
{
  int l = blockIdx.x, s = threadIdx.x;
  const float* Al = A + l*HID*STATE;
  const float* gl = g + l*HID;
  const float* bl = b + l*HID;
  float ga=0.f, ba=0.f;
  for (int j=0;j<HID;j++){
    float a  = Al[j*STATE + s];
    float ap = gl[j]*a;
    Ap[l*HID*STATE + j*STATE + s] = ap;
    ga += ap; ba += bl[j]*a;
  }
  GA[l*STATE+s]=ga; BA[l*STATE+s]=ba;
}

// ---------------------------------------------------------------------------
// U[m][s] = KTAN * ( rstd_m*(h[m]@A'[:,s] - mu_m*GA[s]) + BA[s] )
// M=65536, N=64, K=512.  BM=128, BK=32; 256 threads (16tx x 16ty), 8m x 4n microtile.
__global__ __launch_bounds__(256) void k_ugemm(const float* __restrict__ h,
    const float2* __restrict__ stats, const float* __restrict__ Ap,
    const float* __restrict__ GA, const float* __restrict__ BA,
    float* __restrict__ U)
{
  __shared__ float hsT[32][136];   // [k][m], transposed so a-frag is b128
  __shared__ float Bs[32][68];     // [k][n]
  int m0 = blockIdx.x * 128;
  int tid = threadIdx.x;
  int tx = tid & 15, ty = tid >> 4;
  float acc[8][4] = {};
  for (int kc=0; kc<HID; kc+=32){
    #pragma unroll
    for (int i=0;i<4;i++){
      int idx = tid + i*256;        // 0..1023
      int mr = idx >> 3;            // 0..127
      int kt = idx & 7;
      float4 v = CF4(&h[(m0+mr)*HID + kc + kt*4]);
      hsT[kt*4+0][mr] = v.x;
      hsT[kt*4+1][mr] = v.y;
      hsT[kt*4+2][mr] = v.z;
      hsT[kt*4+3][mr] = v.w;
    }
    #pragma unroll
    for (int i=0;i<2;i++){
      int idx = tid + i*256;        // 0..511 float4s
      int kr = idx >> 4;            // 0..31
      int c4 = idx & 15;
      float4 v = CF4(&Ap[(kc+kr)*STATE + c4*4]);
      F4(&Bs[kr][c4*4]) = v;
    }
    __syncthreads();
    #pragma unroll
    for (int kk=0;kk<32;kk++){
      float4 a0 = CF4(&hsT[kk][ty*8]);
      float4 a1 = CF4(&hsT[kk][ty*8+4]);
      float4 bv = CF4(&Bs[kk][tx*4]);
      float am[8] = {a0.x,a0.y,a0.z,a0.w,a1.x,a1.y,a1.z,a1.w};
      #pragma unroll
      for (int i=0;i<8;i++){
        acc[i][0] = fmaf(am[i], bv.x, acc[i][0]);
        acc[i][1] = fmaf(am[i], bv.y, acc[i][1]);
        acc[i][2] = fmaf(am[i], bv.z, acc[i][2]);
        acc[i][3] = fmaf(am[i], bv.w, acc[i][3]);
      }
    }
    __syncthreads();
  }
  int c0 = tx*4;
  float4 ga = CF4(&GA[c0]);
  float4 ba = CF4(&BA[c0]);
  #pragma unroll
  for (int i=0;i<8;i++){
    int m = m0 + ty*8 + i;
    float2 st = stats[m];
    float4 o;
    o.x = KTAN*(st.y*(acc[i][0] - st.x*ga.x) + ba.x);
    o.y = KTAN*(st.y*(acc[i][1] - st.x*ga.y) + ba.y);
    o.z = KTAN*(st.y*(acc[i][2] - st.x*ga.z) + ba.z);
    o.w = KTAN*(st.y*(acc[i][3] - st.x*ga.w) + ba.w);
    F4(&U[m*STATE + c0]) = o;
  }
}

// ---------------------------------------------------------------------------
// Sequential recurrence. U comes pre-scaled by KTAN. 32 blocks x 64 threads,
// thread (b,s) owns one chain. tanh(x) = 1 - 2/(1+exp2(KTAN*x)).
__global__ __launch_bounds__(64) void k_scan(const float* __restrict__ U,
                                             float* __restrict__ H)
{
  int b = blockIdx.x;
  int s = threadIdx.x;
  const float* Up = U + b*SEQ*STATE + s;
  float* Hp = H + b*SEQ*STATE + s;
  float g = 0.f;                       // KTAN * h_state
  float cur[16], nxt[16];
  #pragma unroll
  for (int i=0;i<16;i++) cur[i] = Up[i*STATE];
  for (int t0=0; t0<SEQ; t0+=16){
    bool has_next = (t0+16 < SEQ);
    if (has_next){
      #pragma unroll
      for (int i=0;i<16;i++) nxt[i] = Up[(t0+16+i)*STATE];
    }
    #pragma unroll
    for (int i=0;i<16;i++){
      float e = fast_exp2(cur[i] + g);
      float r = fast_rcp(1.f + e);
      Hp[(t0+i)*STATE] = fmaf(-2.f, r, 1.f);     // tanh
      g = fmaf(-2.f*KTAN, r, KTAN);              // KTAN*tanh
    }
    if (has_next){
      #pragma unroll
      for (int i=0;i<16;i++) cur[i] = nxt[i];
    }
  }
}

// ---------------------------------------------------------------------------
// In-place epilogue: h[m][j] += H[m]@C[j] + xn[m][j]*D[j]; also emits next-layer
// row stats. M-tile 64, full 512-col sweep in 64-wide chunks, K=64.
// 128 threads (16tx x 8ty), 8m x 4j microtile.
__global__ __launch_bounds__(128) void k_yep(
    float* __restrict__ h, const float* __restrict__ Hg,
    const float* __restrict__ C, const float* __restrict__ Dl,
    const float* __restrict__ gl, const float* __restrict__ bl,
    const float2* __restrict__ stats_in, float2* __restrict__ stats_out)
{
  __shared__ float HshT[STATE][68];   // [s][m-local]
  __shared__ float CshT[STATE][68];   // [s][j-local]
  int m0 = blockIdx.x * 64;
  int tid = threadIdx.x;
  int tx = tid & 15, ty = tid >> 4;   // ty 0..7
  #pragma unroll
  for (int i=0;i<8;i++){
    int idx = tid + i*128;            // 0..1023
    int mr = idx >> 4;                // 0..63
    int s4 = idx & 15;
    float4 v = CF4(&Hg[(m0+mr)*STATE + s4*4]);
    HshT[s4*4+0][mr] = v.x;
    HshT[s4*4+1][mr] = v.y;
    HshT[s4*4+2][mr] = v.z;
    HshT[s4*4+3][mr] = v.w;
  }
  float2 st[8];
  #pragma unroll
  for (int mi=0;mi<8;mi++) st[mi] = stats_in[m0 + ty*8 + mi];
  float sum[8] = {}, sq[8] = {};
  for (int jc=0;jc<HID;jc+=64){
    #pragma unroll
    for (int i=0;i<8;i++){
      int idx = tid + i*128;
      int jr = idx >> 4;
      int s4 = idx & 15;
      float4 v = CF4(&C[(jc+jr)*STATE + s4*4]);
      CshT[s4*4+0][jr] = v.x;
      CshT[s4*4+1][jr] = v.y;
      CshT[s4*4+2][jr] = v.z;
      CshT[s4*4+3][jr] = v.w;
    }
    __syncthreads();
    float acc[8][4] = {};
    #pragma unroll
    for (int s=0;s<STATE;s++){
      float4 cv = CF4(&CshT[s][tx*4]);
      float4 h0 = CF4(&HshT[s][ty*8]);
      float4 h1 = CF4(&HshT[s][ty*8+4]);
      float hm[8] = {h0.x,h0.y,h0.z,h0.w,h1.x,h1.y,h1.z,h1.w};
      #pragma unroll
      for (int mi=0;mi<8;mi++){
        acc[mi][0] = fmaf(hm[mi], cv.x, acc[mi][0]);
        acc[mi][1] = fmaf(hm[mi], cv.y, acc[mi][1]);
        acc[mi][2] = fmaf(hm[mi], cv.z, acc[mi][2]);
        acc[mi][3] = fmaf(hm[mi], cv.w, acc[mi][3]);
      }
    }
    int j0 = jc + tx*4;
    float4 g4 = CF4(&gl[j0]);
    float4 b4 = CF4(&bl[j0]);
    float4 d4 = CF4(&Dl[j0]);
    #pragma unroll
    for (int mi=0;mi<8;mi++){
      int m = m0 + ty*8 + mi;
      float4 hv = CF4(&h[m*HID + j0]);
      float mu = st[mi].x, rs = st[mi].y;
      float4 o;
      o.x = hv.x + acc[mi][0] + fmaf((hv.x - mu)*rs, g4.x, b4.x)*d4.x;
      o.y = hv.y + acc[mi][1] + fmaf((hv.y - mu)*rs, g4.y, b4.y)*d4.y;
      o.z = hv.z + acc[mi][2] + fmaf((hv.z - mu)*rs, g4.z, b4.z)*d4.z;
      o.w = hv.w + acc[mi][3] + fmaf((hv.w - mu)*rs, g4.w, b4.w)*d4.w;
      F4(&h[m*HID + j0]) = o;
      sum[mi] += (o.x+o.y)+(o.z+o.w);
      sq[mi]  += (o.x*o.x+o.y*o.y)+(o.z*o.z+o.w*o.w);
    }
    __syncthreads();
  }
  #pragma unroll
  for (int mi=0;mi<8;mi++){
    float s_ = sum[mi], q = sq[mi];
    #pragma unroll
    for (int off=8; off; off>>=1){
      s_ += __shfl_xor(s_, off);
      q  += __shfl_xor(q,  off);
    }
    if (tx==0){
      float mu  = s_*(1.f/HID);
      float var = q*(1.f/HID) - mu*mu;
      stats_out[m0 + ty*8 + mi] = make_float2(mu, rsqrtf(fmaxf(var,0.f)+EPS));
    }
  }
}

// ---------------------------------------------------------------------------
// Final LN (stats precomputed) on last token + MLP head. 32 blocks x 256 thr.
__global__ __launch_bounds__(256) void k_head(const float* __restrict__ h,
   const float2* __restrict__ stats, const float* __restrict__ ng, const float* __restrict__ nb,
   const float* __restrict__ W1, const float* __restrict__ b1,
   const float* __restrict__ W2, const float* __restrict__ b2,
   float* __restrict__ out)
{
  int bb = blockIdx.x;
  int m = bb*SEQ + (SEQ-1);
  int tid = threadIdx.x;
  __shared__ float xs[HID];
  __shared__ float red[8];
  float2 st = stats[m];
  #pragma unroll
  for (int i=0;i<2;i++){
    int j = tid + i*256;
    float v = h[m*HID + j];
    xs[j] = fmaf((v - st.x)*st.y, ng[j], nb[j]);
  }
  __syncthreads();
  float acc = b1[tid];
  #pragma unroll 8
  for (int j=0;j<HID;j++) acc = fmaf(xs[j], W1[j*(HID/2) + tid], acc);
  float ge = 0.5f*acc*(1.f + erff(acc*0.70710678118654752f));
  float p0 = ge*W2[tid*2+0];
  float p1 = ge*W2[tid*2+1];
  #pragma unroll
  for (int off=32; off; off>>=1){ p0 += __shfl_down(p0, off); p1 += __shfl_down(p1, off); }
  int wid = tid>>6;
  if ((tid&63)==0){ red[wid*2]=p0; red[wid*2+1]=p1; }
  __syncthreads();
  if (tid==0){
    float o0=b2[0], o1=b2[1];
    #pragma unroll
    for (int w=0;w<4;w++){ o0+=red[w*2]; o1+=red[w*2+1]; }
    out[bb*2+0]=o0; out[bb*2+1]=o1;
  }
}

// ---------------------------------------------------------------------------
extern "C" void kernel_launch(void* const* d_in, const int* in_sizes, int n_in,
                              void* d_out, int out_size, void* d_ws, size_t ws_size,
                              hipStream_t stream)
{
  (void)in_sizes; (void)n_in; (void)out_size; (void)ws_size;
  const float* x   = (const float*)d_in[0];
  const float* Win = (const float*)d_in[1];
  const float* bin = (const float*)d_in[2];
  const float* A   = (const float*)d_in[3];
  const float* C   = (const float*)d_in[4];
  const float* Dv  = (const float*)d_in[5];
  const float* lng = (const float*)d_in[6];
  const float* lnb = (const float*)d_in[7];
  const float* ng  = (const float*)d_in[8];
  const float* nb  = (const float*)d_in[9];
  const float* W1  = (const float*)d_in[10];
  const float* b1  = (const float*)d_in[11];
  const float* W2  = (const float*)d_in[12];
  const float* b2  = (const float*)d_in[13];
  float* out = (float*)d_out;
  char* ws = (char*)d_ws;
  // workspace layout (bytes)
  float*  hbuf = (float*)(ws + 0);                       // 134,217,728
  float*  Ubuf = (float*)(ws + (size_t)134217728);       //  16,777,216
  float*  Hbuf = (float*)(ws + (size_t)150994944);       //  16,777,216
  float2* st0  = (float2*)(ws + (size_t)167772160);      //     524,288
  float2* st1  = (float2*)(ws + (size_t)168296448);      //     524,288
  float*  Ap   = (float*)(ws + (size_t)168820736);       //     524,288
  float*  GAb  = (float*)(ws + (size_t)169345024);       //       1,024
  float*  BAb  = (float*)(ws + (size_t)169346048);       //       1,024

  hipLaunchKernelGGL(k_prep,  dim3(NLAYERS), dim3(64),  0, stream, A, lng, lnb, Ap, GAb, BAb);
  hipLaunchKernelGGL(k_input, dim3(NTOK),    dim3(256), 0, stream, x, Win, bin, hbuf, st0);
  float2* scur = st0; float2* snxt = st1;
  for (int l=0; l<NLAYERS; ++l){
    hipLaunchKernelGGL(k_ugemm, dim3(NTOK/128), dim3(256), 0, stream,
        hbuf, scur, Ap + l*HID*STATE, GAb + l*STATE, BAb + l*STATE, Ubuf);
    hipLaunchKernelGGL(k_scan,  dim3(BATCH),    dim3(64),  0, stream, Ubuf, Hbuf);
    hipLaunchKernelGGL(k_yep,   dim3(NTOK/64),  dim3(128), 0, stream,
        hbuf, Hbuf, C + l*HID*STATE, Dv + l*HID, lng + l*HID, lnb + l*HID, scur, snxt);
    float2* t = scur; scur = snxt; snxt = t;
  }
  hipLaunchKernelGGL(k_head, dim3(BATCH), dim3(256), 0, stream,
      hbuf, scur, ng, nb, W1, b1, W2, b2, out);
}